// Round 1
// baseline (4537.617 us; speedup 1.0000x reference)
//
#include <hip/hip_runtime.h>
#include <math.h>

#define LSEQ 4096
#define HCH  256
#define N2   32
#define NLAYERS 4

// ---------------- precompute per-layer discretized params ----------------
__global__ void precomp_k(const float* __restrict__ log_dt, const float* __restrict__ Cre,
                          const float* __restrict__ Cim, const float* __restrict__ lAre,
                          const float* __restrict__ Aim_, float* __restrict__ wre,
                          float* __restrict__ wim, float* __restrict__ c2re, float* __restrict__ c2im)
{
    int idx = blockIdx.x * 256 + threadIdx.x;          // li*H*N2 + h*N2 + n
    if (idx >= NLAYERS * HCH * N2) return;
    int hh = (idx >> 5) & (HCH - 1);
    int li = idx >> 13;
    float dt  = expf(log_dt[(li << 8) + hh]);
    float Are = -expf(lAre[idx]);
    float Aim = Aim_[idx];
    float dre = Are * dt, dim = Aim * dt;
    float er = expf(dre);
    float wr = er * cosf(dim), wi = er * sinf(dim);
    float e1r = wr - 1.0f, e1i = wi;
    float inv = 1.0f / (Are * Are + Aim * Aim);
    float qr = (e1r * Are + e1i * Aim) * inv;
    float qi = (e1i * Are - e1r * Aim) * inv;
    float cr = Cre[idx], ci = Cim[idx];
    wre[idx] = wr;  wim[idx] = wi;
    c2re[idx] = 2.0f * (cr * qr - ci * qi);
    c2im[idx] = 2.0f * (cr * qi + ci * qr);
}

// ---------------- encoder: h[b,hc,l] = sum_i x[b,l,i] * ew[i,hc] + eb[hc] ----------------
__global__ __launch_bounds__(256) void encoder_k(const float* __restrict__ x,
                                                 const float* __restrict__ ew,
                                                 const float* __restrict__ eb,
                                                 float* __restrict__ h)
{
    int l = blockIdx.x * 256 + threadIdx.x;
    int hc = blockIdx.y;
    int b  = blockIdx.z;
    const float* xp = x + ((size_t)b * LSEQ + l) * 8;
    float4 xa = *(const float4*)xp;
    float4 xb = *(const float4*)(xp + 4);
    float acc = eb[hc];
    acc = fmaf(xa.x, ew[0 * HCH + hc], acc);
    acc = fmaf(xa.y, ew[1 * HCH + hc], acc);
    acc = fmaf(xa.z, ew[2 * HCH + hc], acc);
    acc = fmaf(xa.w, ew[3 * HCH + hc], acc);
    acc = fmaf(xb.x, ew[4 * HCH + hc], acc);
    acc = fmaf(xb.y, ew[5 * HCH + hc], acc);
    acc = fmaf(xb.z, ew[6 * HCH + hc], acc);
    acc = fmaf(xb.w, ew[7 * HCH + hc], acc);
    h[((size_t)b * HCH + hc) * LSEQ + l] = acc;
}

// ---------------- S4D recurrence + skip + exact GELU ----------------
// half-wave (32 lanes) per (b,h) row, one complex mode per lane.
__global__ __launch_bounds__(256) void s4d_scan(const float* __restrict__ z,
    const float* __restrict__ wre_, const float* __restrict__ wim_,
    const float* __restrict__ c2re_, const float* __restrict__ c2im_,
    const float* __restrict__ dskip_, float* __restrict__ y, int li)
{
    int tid  = threadIdx.x;
    int lane = tid & 63;
    int half = lane >> 5;
    int n    = lane & 31;
    int wave = tid >> 6;
    int pair = blockIdx.x * 8 + wave * 2 + half;       // global (b,h)
    int b    = pair >> 8;
    int hch  = pair & (HCH - 1);
    const float* zrow = z + ((size_t)b * HCH + hch) * LSEQ;
    float*       yrow = y + ((size_t)b * HCH + hch) * LSEQ;
    int pidx = ((li * HCH + hch) * N2) + n;
    float wre  = wre_[pidx],  wim  = wim_[pidx];
    float c2re = c2re_[pidx], c2im = c2im_[pidx];
    float dsk  = dskip_[li * HCH + hch];
    float sre = 0.f, sim = 0.f;
    int srcbase = lane & 32;
    for (int l0 = 0; l0 < LSEQ; l0 += 32) {
        float zv = zrow[l0 + n];
        float ykeep = 0.f;
        #pragma unroll
        for (int j = 0; j < 32; ++j) {
            float zj = __shfl(zv, srcbase | j);
            float u  = wim * sre;
            float t0 = fmaf(wre, sre, zj);
            sre = fmaf(-wim, sim, t0);
            sim = fmaf(wre, sim, u);
            float c = fmaf(c2re, sre, -c2im * sim);
            c += __shfl_xor(c, 1);
            c += __shfl_xor(c, 2);
            c += __shfl_xor(c, 4);
            c += __shfl_xor(c, 8);
            c += __shfl_xor(c, 16);
            if (n == j) ykeep = c;
        }
        float yv = fmaf(zv, dsk, ykeep);
        float ge = 0.5f * yv * (1.0f + erff(yv * 0.70710678118654752f));
        yrow[l0 + n] = ge;
    }
}

// ---------------- fused 1x1 conv H->2H + GLU + residual ----------------
// t[b,o,l] = a*sigmoid(g) + hin[b,o,l];  a = ow[o,:]@y, g = ow[o+256,:]@y (+ biases)
#define KT 16
__global__ __launch_bounds__(256) void gemmglu_k(const float* __restrict__ y,
    const float* __restrict__ ow, const float* __restrict__ ob,
    const float* __restrict__ hin, float* __restrict__ t, int li)
{
    __shared__ float yt[KT][68];
    __shared__ float wat[KT][68];
    __shared__ float wgt[KT][68];
    int tid = threadIdx.x;
    int l0 = blockIdx.x * 64;
    int o0 = blockIdx.y * 64;
    int b  = blockIdx.z;
    const float* ybase = y + (size_t)b * HCH * LSEQ;
    const float* owl = ow + (size_t)li * 2 * HCH * HCH;
    const float* obl = ob + li * 2 * HCH;
    float accA[4][4] = {{0}};
    float accG[4][4] = {{0}};
    int to = tid >> 4, tl = tid & 15;
    int ld_kk = tid >> 4, ld_l4 = (tid & 15) * 4;
    int ld_oo = tid >> 2, ld_k4 = (tid & 3) * 4;
    for (int k0 = 0; k0 < HCH; k0 += KT) {
        float4 yv  = *(const float4*)(ybase + (size_t)(k0 + ld_kk) * LSEQ + l0 + ld_l4);
        float4 wav = *(const float4*)(owl + (size_t)(o0 + ld_oo) * HCH + k0 + ld_k4);
        float4 wgv = *(const float4*)(owl + (size_t)(o0 + ld_oo + HCH) * HCH + k0 + ld_k4);
        __syncthreads();
        *(float4*)&yt[ld_kk][ld_l4] = yv;
        wat[ld_k4 + 0][ld_oo] = wav.x;
        wat[ld_k4 + 1][ld_oo] = wav.y;
        wat[ld_k4 + 2][ld_oo] = wav.z;
        wat[ld_k4 + 3][ld_oo] = wav.w;
        wgt[ld_k4 + 0][ld_oo] = wgv.x;
        wgt[ld_k4 + 1][ld_oo] = wgv.y;
        wgt[ld_k4 + 2][ld_oo] = wgv.z;
        wgt[ld_k4 + 3][ld_oo] = wgv.w;
        __syncthreads();
        #pragma unroll
        for (int kk = 0; kk < KT; ++kk) {
            float4 av  = *(const float4*)&wat[kk][to * 4];
            float4 gv  = *(const float4*)&wgt[kk][to * 4];
            float4 yv2 = *(const float4*)&yt[kk][tl * 4];
            float aa[4] = {av.x, av.y, av.z, av.w};
            float gg[4] = {gv.x, gv.y, gv.z, gv.w};
            float yy[4] = {yv2.x, yv2.y, yv2.z, yv2.w};
            #pragma unroll
            for (int i = 0; i < 4; ++i)
                #pragma unroll
                for (int j = 0; j < 4; ++j) {
                    accA[i][j] = fmaf(aa[i], yy[j], accA[i][j]);
                    accG[i][j] = fmaf(gg[i], yy[j], accG[i][j]);
                }
        }
    }
    #pragma unroll
    for (int i = 0; i < 4; ++i) {
        int o = o0 + to * 4 + i;
        float oba = obl[o], obg = obl[o + HCH];
        const float* hrow = hin + ((size_t)b * HCH + o) * LSEQ + l0 + tl * 4;
        float4 hv = *(const float4*)hrow;
        float hh[4] = {hv.x, hv.y, hv.z, hv.w};
        float tv[4];
        #pragma unroll
        for (int j = 0; j < 4; ++j) {
            float a = accA[i][j] + oba;
            float g = accG[i][j] + obg;
            float s = 1.0f / (1.0f + expf(-g));
            tv[j] = fmaf(a, s, hh[j]);
        }
        float4 o4 = {tv[0], tv[1], tv[2], tv[3]};
        *(float4*)(t + ((size_t)b * HCH + o) * LSEQ + l0 + tl * 4) = o4;
    }
}

// ---------------- LN stats over channel axis per (b,l) ----------------
__global__ __launch_bounds__(256) void lnstats_k(const float* __restrict__ t,
                                                 float* __restrict__ mu, float* __restrict__ rs)
{
    int lt = threadIdx.x & 63, hg = threadIdx.x >> 6;
    int l = blockIdx.x * 64 + lt;
    int b = blockIdx.y;
    const float* base = t + ((size_t)b * HCH) * LSEQ + l;
    float s = 0.f, q = 0.f;
    for (int h = hg * 64; h < hg * 64 + 64; ++h) {
        float v = base[(size_t)h * LSEQ];
        s += v;
        q = fmaf(v, v, q);
    }
    __shared__ float ss[4][64], qq[4][64];
    ss[hg][lt] = s; qq[hg][lt] = q;
    __syncthreads();
    if (threadIdx.x < 64) {
        float S = ss[0][lt] + ss[1][lt] + ss[2][lt] + ss[3][lt];
        float Q = qq[0][lt] + qq[1][lt] + qq[2][lt] + qq[3][lt];
        float m = S * (1.0f / HCH);
        float v = Q * (1.0f / HCH) - m * m;
        mu[(size_t)b * LSEQ + l] = m;
        rs[(size_t)b * LSEQ + l] = rsqrtf(fmaxf(v, 0.f) + 1e-5f);
    }
}

// ---------------- LN normalize ----------------
__global__ __launch_bounds__(256) void lnnorm_k(const float* __restrict__ t,
    const float* __restrict__ mu, const float* __restrict__ rs,
    const float* __restrict__ g, const float* __restrict__ bln,
    float* __restrict__ hout, int li)
{
    size_t idx = (size_t)blockIdx.x * 256 + threadIdx.x;
    int l = idx & (LSEQ - 1);
    size_t r = idx >> 12;
    int h = r & (HCH - 1);
    int b = (int)(r >> 8);
    size_t bl = ((size_t)b << 12) + l;
    float v = (t[idx] - mu[bl]) * rs[bl] * g[li * HCH + h] + bln[li * HCH + h];
    hout[idx] = v;
}

// ---------------- depthwise conv K=5 same ----------------
__global__ __launch_bounds__(256) void dwconv_k(const float* __restrict__ in,
                                                const float* __restrict__ cw,
                                                float* __restrict__ out)
{
    size_t idx = (size_t)blockIdx.x * 256 + threadIdx.x;
    int l = idx & (LSEQ - 1);
    size_t r = idx >> 12;
    int h = r & (HCH - 1);
    size_t rowbase = idx - l;
    float acc = 0.f;
    #pragma unroll
    for (int j = 0; j < 5; ++j) {
        int ll = l + j - 2;
        if (ll >= 0 && ll < LSEQ)
            acc = fmaf(cw[h * 5 + j], in[rowbase + ll], acc);
    }
    out[idx] = acc;
}

// ---------------- decoder: out[b,l] = sum_h hc[b,h,l]*dw[h] + db ----------------
__global__ __launch_bounds__(256) void decoder_k(const float* __restrict__ hc,
    const float* __restrict__ dw, const float* __restrict__ db, float* __restrict__ out)
{
    int l = blockIdx.x * 256 + threadIdx.x;
    int b = blockIdx.y;
    const float* base = hc + (size_t)b * HCH * LSEQ + l;
    float acc = db[0];
    for (int h = 0; h < HCH; ++h)
        acc = fmaf(dw[h], base[(size_t)h * LSEQ], acc);
    out[(size_t)b * LSEQ + l] = acc;
}

extern "C" void kernel_launch(void* const* d_in, const int* in_sizes, int n_in,
                              void* d_out, int out_size, void* d_ws, size_t ws_size,
                              hipStream_t stream)
{
    const float* x      = (const float*)d_in[0];
    const float* enc_w  = (const float*)d_in[1];
    const float* enc_b  = (const float*)d_in[2];
    const float* log_dt = (const float*)d_in[3];
    const float* C_re   = (const float*)d_in[4];
    const float* C_im   = (const float*)d_in[5];
    const float* lAre   = (const float*)d_in[6];
    const float* A_im   = (const float*)d_in[7];
    const float* D_skip = (const float*)d_in[8];
    const float* out_w  = (const float*)d_in[9];
    const float* out_b  = (const float*)d_in[10];
    const float* ln_g   = (const float*)d_in[11];
    const float* ln_b   = (const float*)d_in[12];
    const float* conv_w = (const float*)d_in[13];
    const float* dec_w  = (const float*)d_in[14];
    const float* dec_b  = (const float*)d_in[15];

    const size_t NTOK = (size_t)16 * HCH * LSEQ;   // 16.78M
    float* ws    = (float*)d_ws;
    float* buf_h = ws;
    float* buf_y = ws + NTOK;
    float* buf_t = ws + 2 * NTOK;
    float* mu    = ws + 3 * NTOK;
    float* rs    = mu + (size_t)16 * LSEQ;
    float* wre   = rs + (size_t)16 * LSEQ;
    float* wim   = wre + NLAYERS * HCH * N2;
    float* c2re  = wim + NLAYERS * HCH * N2;
    float* c2im  = c2re + NLAYERS * HCH * N2;

    precomp_k<<<128, 256, 0, stream>>>(log_dt, C_re, C_im, lAre, A_im, wre, wim, c2re, c2im);
    encoder_k<<<dim3(LSEQ / 256, HCH, 16), 256, 0, stream>>>(x, enc_w, enc_b, buf_h);
    for (int li = 0; li < NLAYERS; ++li) {
        s4d_scan<<<512, 256, 0, stream>>>(buf_h, wre, wim, c2re, c2im, D_skip, buf_y, li);
        gemmglu_k<<<dim3(LSEQ / 64, 4, 16), 256, 0, stream>>>(buf_y, out_w, out_b, buf_h, buf_t, li);
        lnstats_k<<<dim3(LSEQ / 64, 16), 256, 0, stream>>>(buf_t, mu, rs);
        lnnorm_k<<<(int)(NTOK / 256), 256, 0, stream>>>(buf_t, mu, rs, ln_g, ln_b, buf_h, li);
    }
    dwconv_k<<<(int)(NTOK / 256), 256, 0, stream>>>(buf_h, conv_w, buf_y);
    decoder_k<<<dim3(LSEQ / 256, 16), 256, 0, stream>>>(buf_y, dec_w, dec_b, (float*)d_out);
}

// Round 14
// 1795.486 us; speedup vs baseline: 2.5272x; 2.5272x over previous
//
#include <hip/hip_runtime.h>
#include <math.h>

#define LSEQ 4096
#define HCH  256
#define N2   32
#define NLAYERS 4

typedef __attribute__((ext_vector_type(8))) short short8;
typedef __attribute__((ext_vector_type(4))) float f32x4;

__device__ __forceinline__ unsigned short f2bf(float x) {
    unsigned int u = __float_as_uint(x);
    unsigned int r = (u + 0x7FFFu + ((u >> 16) & 1u)) >> 16;   // RNE
    return (unsigned short)r;
}

// ---------------- precompute per-layer discretized params ----------------
__global__ void precomp_k(const float* __restrict__ log_dt, const float* __restrict__ Cre,
                          const float* __restrict__ Cim, const float* __restrict__ lAre,
                          const float* __restrict__ Aim_, float* __restrict__ wre,
                          float* __restrict__ wim, float* __restrict__ c2re, float* __restrict__ c2im)
{
    int idx = blockIdx.x * 256 + threadIdx.x;          // li*H*N2 + h*N2 + n
    if (idx >= NLAYERS * HCH * N2) return;
    int hh = (idx >> 5) & (HCH - 1);
    int li = idx >> 13;
    float dt  = expf(log_dt[(li << 8) + hh]);
    float Are = -expf(lAre[idx]);
    float Aim = Aim_[idx];
    float dre = Are * dt, dim = Aim * dt;
    float er = expf(dre);
    float wr = er * cosf(dim), wi = er * sinf(dim);
    float e1r = wr - 1.0f, e1i = wi;
    float inv = 1.0f / (Are * Are + Aim * Aim);
    float qr = (e1r * Are + e1i * Aim) * inv;
    float qi = (e1i * Are - e1r * Aim) * inv;
    float cr = Cre[idx], ci = Cim[idx];
    wre[idx] = wr;  wim[idx] = wi;
    c2re[idx] = 2.0f * (cr * qr - ci * qi);
    c2im[idx] = 2.0f * (cr * qi + ci * qr);
}

// ---------------- pack out_w into MFMA A-fragment layout, bf16 ----------------
// wpack[li][ot(32)][ks(8)][lane(64)][8]; (o,k): o = ot*16+(lane&15), k = ks*32+(lane>>4)*8+i
__global__ __launch_bounds__(256) void wpack_k(const float* __restrict__ ow,
                                               unsigned short* __restrict__ wpack)
{
    int f  = blockIdx.x * 256 + threadIdx.x;           // 16384 frag-lanes per layer
    int li = blockIdx.y;
    int lane = f & 63, ks = (f >> 6) & 7, ot = f >> 9;
    int o = ot * 16 + (lane & 15);
    int k = ks * 32 + (lane >> 4) * 8;
    const float* src = ow + ((size_t)li * 512 + o) * HCH + k;
    unsigned int out[4];
    #pragma unroll
    for (int i2 = 0; i2 < 4; ++i2)
        out[i2] = (unsigned)f2bf(src[2 * i2]) | ((unsigned)f2bf(src[2 * i2 + 1]) << 16);
    *(uint4*)(wpack + (((size_t)li * 16384) + f) * 8) = *(uint4*)out;
}

// ---------------- encoder: h[b,hc,l] = sum_i x[b,l,i] * ew[i,hc] + eb[hc] ----------------
__global__ __launch_bounds__(256) void encoder_k(const float* __restrict__ x,
                                                 const float* __restrict__ ew,
                                                 const float* __restrict__ eb,
                                                 float* __restrict__ h)
{
    int l = blockIdx.x * 256 + threadIdx.x;
    int hc = blockIdx.y;
    int b  = blockIdx.z;
    const float* xp = x + ((size_t)b * LSEQ + l) * 8;
    float4 xa = *(const float4*)xp;
    float4 xb = *(const float4*)(xp + 4);
    float acc = eb[hc];
    acc = fmaf(xa.x, ew[0 * HCH + hc], acc);
    acc = fmaf(xa.y, ew[1 * HCH + hc], acc);
    acc = fmaf(xa.z, ew[2 * HCH + hc], acc);
    acc = fmaf(xa.w, ew[3 * HCH + hc], acc);
    acc = fmaf(xb.x, ew[4 * HCH + hc], acc);
    acc = fmaf(xb.y, ew[5 * HCH + hc], acc);
    acc = fmaf(xb.z, ew[6 * HCH + hc], acc);
    acc = fmaf(xb.w, ew[7 * HCH + hc], acc);
    h[((size_t)b * HCH + hc) * LSEQ + l] = acc;
}

// ---------------- S4D recurrence + skip + exact GELU + bf16 fragment store ----------------
// half-wave (32 lanes) per (b,h) row, one complex mode per lane. Deferred
// cross-mode reduce: step j writes ct[j][n]; lane n later sums its row
// ct[n][0..31]. The ct values cross LANES between write and read (lane n's
// read of ct[n][m] was produced by lane m during step n) — a data race the
// compiler may reorder (it can prove read[n][m] never aliases write[j][.]
// for j!=m, so it may sink iter-k reads past iter-k+1 writes). RACE FIX:
// __syncthreads() between write and read phases; the end-of-tile barrier
// (for ylds) orders reads(k) vs writes(k+1). This race was rounds 9/10's
// absmax~2.5 failure.
__global__ __launch_bounds__(256) void s4d_scan(const float* __restrict__ z,
    const float* __restrict__ wre_, const float* __restrict__ wim_,
    const float* __restrict__ c2re_, const float* __restrict__ c2im_,
    const float* __restrict__ dskip_, unsigned short* __restrict__ yfrag, int li)
{
    __shared__ float ct[8][32][33];
    __shared__ unsigned short ylds[2][8][32];
    int tid  = threadIdx.x;
    int lane = tid & 63;
    int half = lane >> 5;
    int n    = lane & 31;
    int wave = tid >> 6;
    int hw   = wave * 2 + half;
    int pair = blockIdx.x * 8 + hw;                    // global (b,h)
    int b    = pair >> 8;
    int hch  = pair & (HCH - 1);
    const float* zrow = z + ((size_t)b * HCH + hch) * LSEQ;
    int pidx = ((li * HCH + hch) * N2) + n;
    float wre  = wre_[pidx],  wim  = wim_[pidx];
    float c2re = c2re_[pidx], c2im = c2im_[pidx];
    float dsk  = dskip_[li * HCH + hch];
    float sre = 0.f, sim = 0.f;
    int srcbase = lane & 32;
    // fragment-store constants (block covers h0..h0+7, h0 = (blockIdx.x*8)&255)
    int kq = blockIdx.x & 3;                           // (h0&31)>>3
    int ks = ((blockIdx.x * 8) & 255) >> 5;
    int bb = blockIdx.x >> 5;
    float zv = zrow[n];                                // prefetch tile 0
    int buf = 0;
    for (int l0 = 0; l0 < LSEQ; l0 += 32, buf ^= 1) {
        float znext = (l0 + 32 < LSEQ) ? zrow[l0 + 32 + n] : 0.f;
        #pragma unroll
        for (int j = 0; j < 32; ++j) {
            float zj = __shfl(zv, srcbase | j);
            float u  = wim * sre;
            float t0 = fmaf(wre, sre, zj);
            sre = fmaf(-wim, sim, t0);
            sim = fmaf(wre, sim, u);
            ct[hw][j][n] = fmaf(c2re, sre, -c2im * sim);
        }
        __syncthreads();                               // RACE FIX: order ct writes -> reads
        float acc = 0.f;
        #pragma unroll
        for (int m = 0; m < 32; ++m) acc += ct[hw][n][m];   // row n = step n, sum modes
        float yv = fmaf(zv, dsk, acc);
        float ge = 0.5f * yv * (1.0f + erff(yv * 0.70710678118654752f));
        ylds[buf][hw][n] = f2bf(ge);
        __syncthreads();                               // orders ylds w->r AND ct reads(k)->writes(k+1)
        if (tid < 32) {                                // pack 8 h-values -> 16B frag-lane
            int t = tid;
            int lt = (l0 + t) >> 4;
            unsigned int out[4];
            #pragma unroll
            for (int i2 = 0; i2 < 4; ++i2)
                out[i2] = (unsigned)ylds[buf][2 * i2][t] | ((unsigned)ylds[buf][2 * i2 + 1][t] << 16);
            size_t off = (((size_t)bb * 256 + lt) * 8 + ks) * 64 + (kq * 16 + (t & 15));
            *(uint4*)(yfrag + off * 8) = *(uint4*)out;
        }
        zv = znext;
    }
}

// ---------------- MFMA 1x1 conv H->2H + GLU + residual ----------------
// t[b,o,l] = a*sigmoid(g) + hin; A = wpack (bf16 frags), B = yfrag (bf16 frags).
// Block: b fixed, 64-l tile, all 512 o. Wave w: a-channels [w*64,w*64+64),
// g-channels +256 (intra-wave GLU pairing, same lane/reg).
__global__ __launch_bounds__(256) void gemmglu_k(const unsigned short* __restrict__ yfrag,
    const unsigned short* __restrict__ wpack, const float* __restrict__ ob,
    const float* __restrict__ hin, float* __restrict__ t, int li)
{
    int tid  = threadIdx.x;
    int wave = tid >> 6, lane = tid & 63;
    int b  = blockIdx.y;
    int l0 = blockIdx.x * 64;
    const unsigned short* yfb = yfrag + ((size_t)b * 256 + blockIdx.x * 4) * 4096; // [ltl][ks][lane][8]
    const unsigned short* wpl = wpack + (size_t)li * 16384 * 8;
    const float* obl = ob + li * 512;
    int kq = lane >> 4, col = lane & 15;
    #pragma unroll
    for (int lsub = 0; lsub < 4; ++lsub) {
        short8 Bf[8];
        #pragma unroll
        for (int ks = 0; ks < 8; ++ks)
            Bf[ks] = *(const short8*)(yfb + (((size_t)lsub * 8 + ks) * 64 + lane) * 8);
        #pragma unroll
        for (int p = 0; p < 4; ++p) {
            int otA = wave * 4 + p;
            f32x4 aA = {0.f, 0.f, 0.f, 0.f};
            f32x4 aG = {0.f, 0.f, 0.f, 0.f};
            #pragma unroll
            for (int ks = 0; ks < 8; ++ks) {
                short8 Af = *(const short8*)(wpl + (((size_t)otA * 8 + ks) * 64 + lane) * 8);
                short8 Gf = *(const short8*)(wpl + ((((size_t)otA + 16) * 8 + ks) * 64 + lane) * 8);
                aA = __builtin_amdgcn_mfma_f32_16x16x32_bf16(Af, Bf[ks], aA, 0, 0, 0);
                aG = __builtin_amdgcn_mfma_f32_16x16x32_bf16(Gf, Bf[ks], aG, 0, 0, 0);
            }
            int oA = otA * 16 + kq * 4;
            int l  = l0 + lsub * 16 + col;
            #pragma unroll
            for (int j = 0; j < 4; ++j) {
                float a = aA[j] + obl[oA + j];
                float g = aG[j] + obl[oA + j + 256];
                float s = 1.0f / (1.0f + expf(-g));
                size_t idx = ((size_t)b * HCH + oA + j) * LSEQ + l;
                t[idx] = fmaf(a, s, hin[idx]);
            }
        }
    }
}

// ---------------- LN stats over channel axis per (b,l) ----------------
__global__ __launch_bounds__(256) void lnstats_k(const float* __restrict__ t,
                                                 float* __restrict__ mu, float* __restrict__ rs)
{
    int lt = threadIdx.x & 63, hg = threadIdx.x >> 6;
    int l = blockIdx.x * 64 + lt;
    int b = blockIdx.y;
    const float* base = t + ((size_t)b * HCH) * LSEQ + l;
    float s = 0.f, q = 0.f;
    for (int h = hg * 64; h < hg * 64 + 64; ++h) {
        float v = base[(size_t)h * LSEQ];
        s += v;
        q = fmaf(v, v, q);
    }
    __shared__ float ss[4][64], qq[4][64];
    ss[hg][lt] = s; qq[hg][lt] = q;
    __syncthreads();
    if (threadIdx.x < 64) {
        float S = ss[0][lt] + ss[1][lt] + ss[2][lt] + ss[3][lt];
        float Q = qq[0][lt] + qq[1][lt] + qq[2][lt] + qq[3][lt];
        float m = S * (1.0f / HCH);
        float v = Q * (1.0f / HCH) - m * m;
        mu[(size_t)b * LSEQ + l] = m;
        rs[(size_t)b * LSEQ + l] = rsqrtf(fmaxf(v, 0.f) + 1e-5f);
    }
}

// ---------------- LN normalize ----------------
__global__ __launch_bounds__(256) void lnnorm_k(const float* __restrict__ t,
    const float* __restrict__ mu, const float* __restrict__ rs,
    const float* __restrict__ g, const float* __restrict__ bln,
    float* __restrict__ hout, int li)
{
    size_t idx = (size_t)blockIdx.x * 256 + threadIdx.x;
    int l = idx & (LSEQ - 1);
    size_t r = idx >> 12;
    int h = r & (HCH - 1);
    int b = (int)(r >> 8);
    size_t bl = ((size_t)b << 12) + l;
    float v = (t[idx] - mu[bl]) * rs[bl] * g[li * HCH + h] + bln[li * HCH + h];
    hout[idx] = v;
}

// ---------------- depthwise conv K=5 same ----------------
__global__ __launch_bounds__(256) void dwconv_k(const float* __restrict__ in,
                                                const float* __restrict__ cw,
                                                float* __restrict__ out)
{
    size_t idx = (size_t)blockIdx.x * 256 + threadIdx.x;
    int l = idx & (LSEQ - 1);
    size_t r = idx >> 12;
    int h = r & (HCH - 1);
    size_t rowbase = idx - l;
    float acc = 0.f;
    #pragma unroll
    for (int j = 0; j < 5; ++j) {
        int ll = l + j - 2;
        if (ll >= 0 && ll < LSEQ)
            acc = fmaf(cw[h * 5 + j], in[rowbase + ll], acc);
    }
    out[idx] = acc;
}

// ---------------- decoder: out[b,l] = sum_h hc[b,h,l]*dw[h] + db ----------------
__global__ __launch_bounds__(256) void decoder_k(const float* __restrict__ hc,
    const float* __restrict__ dw, const float* __restrict__ db, float* __restrict__ out)
{
    int l = blockIdx.x * 256 + threadIdx.x;
    int b = blockIdx.y;
    const float* base = hc + (size_t)b * HCH * LSEQ + l;
    float acc = db[0];
    for (int h = 0; h < HCH; ++h)
        acc = fmaf(dw[h], base[(size_t)h * LSEQ], acc);
    out[(size_t)b * LSEQ + l] = acc;
}

extern "C" void kernel_launch(void* const* d_in, const int* in_sizes, int n_in,
                              void* d_out, int out_size, void* d_ws, size_t ws_size,
                              hipStream_t stream)
{
    const float* x      = (const float*)d_in[0];
    const float* enc_w  = (const float*)d_in[1];
    const float* enc_b  = (const float*)d_in[2];
    const float* log_dt = (const float*)d_in[3];
    const float* C_re   = (const float*)d_in[4];
    const float* C_im   = (const float*)d_in[5];
    const float* lAre   = (const float*)d_in[6];
    const float* A_im   = (const float*)d_in[7];
    const float* D_skip = (const float*)d_in[8];
    const float* out_w  = (const float*)d_in[9];
    const float* out_b  = (const float*)d_in[10];
    const float* ln_g   = (const float*)d_in[11];
    const float* ln_b   = (const float*)d_in[12];
    const float* conv_w = (const float*)d_in[13];
    const float* dec_w  = (const float*)d_in[14];
    const float* dec_b  = (const float*)d_in[15];

    const size_t NTOK = (size_t)16 * HCH * LSEQ;       // 16.78M
    float* ws    = (float*)d_ws;
    float* buf_h = ws;
    float* buf_t = ws + NTOK;
    float* mu    = ws + 2 * NTOK;
    float* rs    = mu + (size_t)16 * LSEQ;
    float* wre   = rs + (size_t)16 * LSEQ;
    float* wim   = wre + NLAYERS * HCH * N2;
    float* c2re  = wim + NLAYERS * HCH * N2;
    float* c2im  = c2re + NLAYERS * HCH * N2;
    unsigned short* wpackp = (unsigned short*)(c2im + NLAYERS * HCH * N2);
    unsigned short* yfrag  = wpackp + (size_t)NLAYERS * 512 * 256;   // NTOK ushorts

    precomp_k<<<128, 256, 0, stream>>>(log_dt, C_re, C_im, lAre, A_im, wre, wim, c2re, c2im);
    wpack_k<<<dim3(64, NLAYERS), 256, 0, stream>>>(out_w, wpackp);
    encoder_k<<<dim3(LSEQ / 256, HCH, 16), 256, 0, stream>>>(x, enc_w, enc_b, buf_h);
    for (int li = 0; li < NLAYERS; ++li) {
        s4d_scan<<<512, 256, 0, stream>>>(buf_h, wre, wim, c2re, c2im, D_skip, yfrag, li);
        gemmglu_k<<<dim3(LSEQ / 64, 16), 256, 0, stream>>>(yfrag, wpackp, out_b, buf_h, buf_t, li);
        lnstats_k<<<dim3(LSEQ / 64, 16), 256, 0, stream>>>(buf_t, mu, rs);
        lnnorm_k<<<(int)(NTOK / 256), 256, 0, stream>>>(buf_t, mu, rs, ln_g, ln_b, buf_h, li);
    }
    dwconv_k<<<(int)(NTOK / 256), 256, 0, stream>>>(buf_h, conv_w, buf_t);
    decoder_k<<<dim3(LSEQ / 256, 16), 256, 0, stream>>>(buf_t, dec_w, dec_b, (float*)d_out);
}